// Round 15
// baseline (477.144 us; speedup 1.0000x reference)
//
#include <hip/hip_runtime.h>

#define HDIM 64
#define CAP_M 96
#define CAP_U 32
#define OVF_MAX 65536

typedef __attribute__((ext_vector_type(8))) short bf16x8;   // 8 bf16 (4 VGPRs)
typedef __attribute__((ext_vector_type(4))) float f32x4;    // 4 fp32

// ---------------- bf16 helpers ----------------
__device__ __forceinline__ float bf2f(unsigned short u) {
  unsigned int x = ((unsigned int)u) << 16;
  return __uint_as_float(x);
}
__device__ __forceinline__ unsigned short f2bf(float f) {
  unsigned int x = __float_as_uint(f);
  unsigned int r = (x + 0x7FFFu + ((x >> 16) & 1u)) >> 16;  // RNE
  return (unsigned short)r;
}

// ---------------- init: zero meta + bf16 table copies ----------------
__global__ __launch_bounds__(256) void k_init(int* __restrict__ meta, int nmeta,
                                              const float* __restrict__ ut,
                                              unsigned short* __restrict__ ub, int n8u,
                                              const float* __restrict__ mt,
                                              unsigned short* __restrict__ mb, int n8m) {
  int bid = blockIdx.x;
  if (bid < 512) {
    int i = bid * 256 + threadIdx.x;
    for (int j = i; j < nmeta; j += 512 * 256) meta[j] = 0;
  } else if (bid < 512 + 2048) {
    int i = (bid - 512) * 256 + threadIdx.x;
    for (int j = i; j < n8u; j += 2048 * 256) {
      const float4* p = (const float4*)(ut + (size_t)j * 8);
      float4 a = p[0], b = p[1];
      uint4 o;
      o.x = (unsigned int)f2bf(a.x) | ((unsigned int)f2bf(a.y) << 16);
      o.y = (unsigned int)f2bf(a.z) | ((unsigned int)f2bf(a.w) << 16);
      o.z = (unsigned int)f2bf(b.x) | ((unsigned int)f2bf(b.y) << 16);
      o.w = (unsigned int)f2bf(b.z) | ((unsigned int)f2bf(b.w) << 16);
      *(uint4*)(ub + (size_t)j * 8) = o;
    }
  } else {
    int i = (bid - 512 - 2048) * 256 + threadIdx.x;
    for (int j = i; j < n8m; j += 512 * 256) {
      const float4* p = (const float4*)(mt + (size_t)j * 8);
      float4 a = p[0], b = p[1];
      uint4 o;
      o.x = (unsigned int)f2bf(a.x) | ((unsigned int)f2bf(a.y) << 16);
      o.y = (unsigned int)f2bf(a.z) | ((unsigned int)f2bf(a.w) << 16);
      o.z = (unsigned int)f2bf(b.x) | ((unsigned int)f2bf(b.y) << 16);
      o.w = (unsigned int)f2bf(b.z) | ((unsigned int)f2bf(b.w) << 16);
      *(uint4*)(mb + (size_t)j * 8) = o;
    }
  }
}

// ---------------- fused bucket fill (r7/r12 proven; atomic floor ~174us) ----------------
__global__ __launch_bounds__(256) void k_fillb2_x(const int* __restrict__ srcU,
                                                  const int* __restrict__ dstM,
                                                  int* __restrict__ curM,
                                                  int* __restrict__ bktM,
                                                  int* __restrict__ ovfM_cnt,
                                                  int* __restrict__ ovfM,
                                                  int* __restrict__ curU,
                                                  unsigned short* __restrict__ bktU,
                                                  int* __restrict__ ovfU_cnt,
                                                  int* __restrict__ ovfU,
                                                  int E, int NM_, int NU_) {
  int xg = blockIdx.x & 7;
  int mlo = (int)(((long long)NM_ * xg) >> 3);
  int mhi = (xg == 7) ? NM_ : (int)(((long long)NM_ * (xg + 1)) >> 3);
  int ulo = (int)(((long long)NU_ * xg) >> 3);
  int uhi = (xg == 7) ? NU_ : (int)(((long long)NU_ * (xg + 1)) >> 3);
  int li = (blockIdx.x >> 3) * blockDim.x + threadIdx.x;
  int stride = (gridDim.x >> 3) * blockDim.x;
  int E4 = E >> 2;
  const int4* s4 = (const int4*)srcU;
  const int4* d4 = (const int4*)dstM;
  for (int e = li; e < E4; e += stride) {
    int4 d = d4[e];
    int4 s = s4[e];
#pragma unroll
    for (int k = 0; k < 4; ++k) {
      int dd = (k == 0) ? d.x : (k == 1) ? d.y : (k == 2) ? d.z : d.w;
      int ss = (k == 0) ? s.x : (k == 1) ? s.y : (k == 2) ? s.z : s.w;
      if (dd >= mlo && dd < mhi) {
        int p = atomicAdd(&curM[dd], 1);
        if (p < CAP_M) bktM[(size_t)dd * CAP_M + p] = ss;
        else { int q = atomicAdd(ovfM_cnt, 1); if (q < OVF_MAX) { ovfM[2 * q] = dd; ovfM[2 * q + 1] = ss; } }
      }
      if (ss >= ulo && ss < uhi) {
        int p = atomicAdd(&curU[ss], 1);
        if (p < CAP_U) bktU[(size_t)ss * CAP_U + p] = (unsigned short)dd;
        else { int q = atomicAdd(ovfU_cnt, 1); if (q < OVF_MAX) { ovfU[2 * q] = ss; ovfU[2 * q + 1] = dd; } }
      }
    }
  }
  for (int e = E4 * 4 + li; e < E; e += stride) {
    int dd = dstM[e];
    int ss = srcU[e];
    if (dd >= mlo && dd < mhi) {
      int p = atomicAdd(&curM[dd], 1);
      if (p < CAP_M) bktM[(size_t)dd * CAP_M + p] = ss;
      else { int q = atomicAdd(ovfM_cnt, 1); if (q < OVF_MAX) { ovfM[2 * q] = dd; ovfM[2 * q + 1] = ss; } }
    }
    if (ss >= ulo && ss < uhi) {
      int p = atomicAdd(&curU[ss], 1);
      if (p < CAP_U) bktU[(size_t)ss * CAP_U + p] = (unsigned short)dd;
      else { int q = atomicAdd(ovfU_cnt, 1); if (q < OVF_MAX) { ovfU[2 * q] = ss; ovfU[2 * q + 1] = dd; } }
    }
  }
}

// ---------------- fused SAGE conv: gather+mean directly into MFMA A-frags ----------------
// 512 threads = 8 waves; one wave = 16 nodes (one 16x16 M-tile). Lane l:
// lm=l&15 node-in-tile, lg=l>>4 col-octet. Gather: 4 lanes/node, 2x16B per
// neighbor row, fp32 accumulate -> mean -> bf16 A-frags (k<64); X row frags
// (k>=64). B-frags from LDS W^T (r13-proven layout). C/D m89 mapping; LDS
// transpose staging for coalesced stores. Nodes present in the ovf list are
// skipped (k_redo recomputes them; list empty for this input).
template <typename IT, int OUTBF>
__global__ __launch_bounds__(512) void k_sagex(const unsigned short* __restrict__ xg,
                                               const int* __restrict__ cur,
                                               const IT* __restrict__ bkt, int cap,
                                               const int* __restrict__ ovf_cnt,
                                               const int* __restrict__ ovf,
                                               const unsigned short* __restrict__ X,
                                               const float* __restrict__ Wl,
                                               const float* __restrict__ Wr,
                                               const float* __restrict__ bias,
                                               void* outv, int n_dst, int do_relu) {
  __shared__ unsigned short sWt[64][136];  // W^T bf16 padded, 17.4 KB
  __shared__ float sOut[8][16][68];        // per-wave C staging, 34.8 KB

  int t = threadIdx.x;
  for (int id = t; id < 64 * 128; id += 512) {
    int col = id & 63;
    int k = id >> 6;
    float wv = (k < 64) ? Wl[k * 64 + col] : Wr[(k - 64) * 64 + col];
    sWt[col][k] = f2bf(wv);
  }
  __syncthreads();

  int w = t >> 6;
  int l = t & 63;
  int lm = l & 15;
  int lg = l >> 4;
  int wid = blockIdx.x * 8 + w;
  int nw = gridDim.x * 8;
  int ntiles = (n_dst + 15) >> 4;
  int novf = *ovf_cnt;
  if (novf > OVF_MAX) novf = OVF_MAX;

  for (int tile = wid; tile < ntiles; tile += nw) {
    int nbase = tile << 4;
    int row = nbase + lm;
    int rowc = row < n_dst ? row : (n_dst - 1);
    int deg = cur[rowc];
    int nb = deg < cap ? deg : cap;
    const IT* lst = bkt + (size_t)rowc * cap;

    // ---- gather + fp32 accumulate (cols 8lg..+7 and 32+8lg..+7) ----
    float aA0=0,aA1=0,aA2=0,aA3=0,aA4=0,aA5=0,aA6=0,aA7=0;
    float aB0=0,aB1=0,aB2=0,aB3=0,aB4=0,aB5=0,aB6=0,aB7=0;
#define ADD8A(wv) { aA0+=__uint_as_float((wv).x<<16); aA1+=__uint_as_float((wv).x&0xFFFF0000u); \
                    aA2+=__uint_as_float((wv).y<<16); aA3+=__uint_as_float((wv).y&0xFFFF0000u); \
                    aA4+=__uint_as_float((wv).z<<16); aA5+=__uint_as_float((wv).z&0xFFFF0000u); \
                    aA6+=__uint_as_float((wv).w<<16); aA7+=__uint_as_float((wv).w&0xFFFF0000u); }
#define ADD8B(wv) { aB0+=__uint_as_float((wv).x<<16); aB1+=__uint_as_float((wv).x&0xFFFF0000u); \
                    aB2+=__uint_as_float((wv).y<<16); aB3+=__uint_as_float((wv).y&0xFFFF0000u); \
                    aB4+=__uint_as_float((wv).z<<16); aB5+=__uint_as_float((wv).z&0xFFFF0000u); \
                    aB6+=__uint_as_float((wv).w<<16); aB7+=__uint_as_float((wv).w&0xFFFF0000u); }
    int e = 0;
    for (; e + 4 <= nb; e += 4) {
      int i0, i1, i2, i3;
      if (sizeof(IT) == 2) {
        ushort4 ia = *(const ushort4*)&lst[e];
        i0 = ia.x; i1 = ia.y; i2 = ia.z; i3 = ia.w;
      } else {
        int4 ia = *(const int4*)&lst[e];
        i0 = ia.x; i1 = ia.y; i2 = ia.z; i3 = ia.w;
      }
      uint4 p0 = *(const uint4*)&xg[(size_t)i0 * HDIM + 8 * lg];
      uint4 q0 = *(const uint4*)&xg[(size_t)i0 * HDIM + 32 + 8 * lg];
      uint4 p1 = *(const uint4*)&xg[(size_t)i1 * HDIM + 8 * lg];
      uint4 q1 = *(const uint4*)&xg[(size_t)i1 * HDIM + 32 + 8 * lg];
      uint4 p2 = *(const uint4*)&xg[(size_t)i2 * HDIM + 8 * lg];
      uint4 q2 = *(const uint4*)&xg[(size_t)i2 * HDIM + 32 + 8 * lg];
      uint4 p3 = *(const uint4*)&xg[(size_t)i3 * HDIM + 8 * lg];
      uint4 q3 = *(const uint4*)&xg[(size_t)i3 * HDIM + 32 + 8 * lg];
      ADD8A(p0); ADD8B(q0); ADD8A(p1); ADD8B(q1);
      ADD8A(p2); ADD8B(q2); ADD8A(p3); ADD8B(q3);
    }
    for (; e < nb; ++e) {
      int i0 = (int)lst[e];
      uint4 p0 = *(const uint4*)&xg[(size_t)i0 * HDIM + 8 * lg];
      uint4 q0 = *(const uint4*)&xg[(size_t)i0 * HDIM + 32 + 8 * lg];
      ADD8A(p0); ADD8B(q0);
    }
#undef ADD8A
#undef ADD8B

    float inv = deg > 0 ? 1.f / (float)deg : 0.f;
    bf16x8 afr0, afr1;
    afr0[0] = (short)f2bf(aA0 * inv); afr0[1] = (short)f2bf(aA1 * inv);
    afr0[2] = (short)f2bf(aA2 * inv); afr0[3] = (short)f2bf(aA3 * inv);
    afr0[4] = (short)f2bf(aA4 * inv); afr0[5] = (short)f2bf(aA5 * inv);
    afr0[6] = (short)f2bf(aA6 * inv); afr0[7] = (short)f2bf(aA7 * inv);
    afr1[0] = (short)f2bf(aB0 * inv); afr1[1] = (short)f2bf(aB1 * inv);
    afr1[2] = (short)f2bf(aB2 * inv); afr1[3] = (short)f2bf(aB3 * inv);
    afr1[4] = (short)f2bf(aB4 * inv); afr1[5] = (short)f2bf(aB5 * inv);
    afr1[6] = (short)f2bf(aB6 * inv); afr1[7] = (short)f2bf(aB7 * inv);
    bf16x8 afr2 = *(const bf16x8*)&X[(size_t)rowc * HDIM + 8 * lg];
    bf16x8 afr3 = *(const bf16x8*)&X[(size_t)rowc * HDIM + 32 + 8 * lg];

    // ---- MFMA: 4 K-steps x 4 N-tiles ----
    f32x4 zz = {0.f, 0.f, 0.f, 0.f};
    f32x4 acc[4];
#pragma unroll
    for (int n = 0; n < 4; ++n) acc[n] = zz;
#pragma unroll
    for (int s = 0; s < 4; ++s) {
      bf16x8 af = (s == 0) ? afr0 : (s == 1) ? afr1 : (s == 2) ? afr2 : afr3;
#pragma unroll
      for (int n = 0; n < 4; ++n) {
        bf16x8 bfr = *(const bf16x8*)(&sWt[16 * n + lm][32 * s + 8 * lg]);
        acc[n] = __builtin_amdgcn_mfma_f32_16x16x32_bf16(af, bfr, acc[n], 0, 0, 0);
      }
    }

    // ---- bias + relu, stage C, coalesced store ----
#pragma unroll
    for (int n = 0; n < 4; ++n) {
      float bj = bias[16 * n + lm];
#pragma unroll
      for (int r = 0; r < 4; ++r) {
        float v = acc[n][r] + bj;
        if (do_relu) v = fmaxf(v, 0.f);
        sOut[w][lg * 4 + r][16 * n + lm] = v;
      }
    }

    int node = nbase + (l >> 2);
    bool skip = false;
    if (novf > 0) {
      for (int j2 = 0; j2 < novf; ++j2)
        if (ovf[2 * j2] == node) { skip = true; break; }
    }
    if (node < n_dst && !skip) {
      int c0 = (l & 3) * 16;
      float4 o0 = *(const float4*)&sOut[w][l >> 2][c0];
      float4 o1 = *(const float4*)&sOut[w][l >> 2][c0 + 4];
      float4 o2 = *(const float4*)&sOut[w][l >> 2][c0 + 8];
      float4 o3 = *(const float4*)&sOut[w][l >> 2][c0 + 12];
      if (OUTBF) {
        unsigned short* ob = (unsigned short*)outv;
        uint4 p0, p1;
        p0.x = (unsigned int)f2bf(o0.x) | ((unsigned int)f2bf(o0.y) << 16);
        p0.y = (unsigned int)f2bf(o0.z) | ((unsigned int)f2bf(o0.w) << 16);
        p0.z = (unsigned int)f2bf(o1.x) | ((unsigned int)f2bf(o1.y) << 16);
        p0.w = (unsigned int)f2bf(o1.z) | ((unsigned int)f2bf(o1.w) << 16);
        p1.x = (unsigned int)f2bf(o2.x) | ((unsigned int)f2bf(o2.y) << 16);
        p1.y = (unsigned int)f2bf(o2.z) | ((unsigned int)f2bf(o2.w) << 16);
        p1.z = (unsigned int)f2bf(o3.x) | ((unsigned int)f2bf(o3.y) << 16);
        p1.w = (unsigned int)f2bf(o3.z) | ((unsigned int)f2bf(o3.w) << 16);
        *(uint4*)&ob[(size_t)node * HDIM + c0] = p0;
        *(uint4*)&ob[(size_t)node * HDIM + c0 + 8] = p1;
      } else {
        float* of = (float*)outv;
        *(float4*)&of[(size_t)node * HDIM + c0] = o0;
        *(float4*)&of[(size_t)node * HDIM + c0 + 4] = o1;
        *(float4*)&of[(size_t)node * HDIM + c0 + 8] = o2;
        *(float4*)&of[(size_t)node * HDIM + c0 + 12] = o3;
      }
    }
  }
}

// ---------------- cold overflow recompute (no-op when ovf counts are 0) ----------------
__device__ __forceinline__ void redo_side(const int* cnt_p, const int* ovf,
                                          const unsigned short* g, const int* cur,
                                          const void* bkt, int cap, int is16,
                                          const unsigned short* X,
                                          const float* Wl, const float* Wr,
                                          const float* bb, void* out, int obf,
                                          int relu, int bq, float* in) {
  int n = *cnt_p;
  if (n > OVF_MAX) n = OVF_MAX;
  if (n == 0) return;
  int t = threadIdx.x;
  for (int q = bq; q < n; q += 32) {
    int d = ovf[2 * q];
    if (t < 64) {
      float s = 0.f;
      int deg = cur[d];
      int nb = deg < cap ? deg : cap;
      for (int j = 0; j < nb; ++j) {
        int idx = is16 ? (int)((const unsigned short*)bkt)[(size_t)d * cap + j]
                       : ((const int*)bkt)[(size_t)d * cap + j];
        s += bf2f(g[(size_t)idx * HDIM + t]);
      }
      for (int j = 0; j < n; ++j)
        if (ovf[2 * j] == d) s += bf2f(g[(size_t)ovf[2 * j + 1] * HDIM + t]);
      in[t] = s / (float)deg;
      in[64 + t] = bf2f(X[(size_t)d * HDIM + t]);
    }
    __syncthreads();
    if (t < 64) {
      float o = bb[t];
      for (int k = 0; k < 64; ++k) o += in[k] * Wl[k * 64 + t];
      for (int k = 0; k < 64; ++k) o += in[64 + k] * Wr[k * 64 + t];
      if (relu) o = fmaxf(o, 0.f);
      if (obf) ((unsigned short*)out)[(size_t)d * HDIM + t] = f2bf(o);
      else ((float*)out)[(size_t)d * HDIM + t] = o;
    }
    __syncthreads();
  }
}

__global__ __launch_bounds__(128) void k_redo(
    const int* cM, const int* oM, const unsigned short* gM, const int* curM,
    const void* bM, int capM, const unsigned short* XM,
    const float* WlM, const float* WrM, const float* bbM, void* outM, int obfM, int reluM,
    const int* cU, const int* oU, const unsigned short* gU, const int* curU,
    const void* bU, int capU, const unsigned short* XU,
    const float* WlU, const float* WrU, const float* bbU, void* outU, int obfU, int reluU) {
  __shared__ float in[128];
  int b = blockIdx.x;
  if (b < 32)
    redo_side(cM, oM, gM, curM, bM, capM, 0, XM, WlM, WrM, bbM, outM, obfM, reluM, b, in);
  else
    redo_side(cU, oU, gU, curU, bU, capU, 1, XU, WlU, WrU, bbU, outU, obfU, reluU, b - 32, in);
}

// ---------------- path-B finalize: expand u2 bf16 -> fp32, copy m2 ----------------
__global__ __launch_bounds__(256) void k_final(const unsigned short* __restrict__ ubuf,
                                               const float* __restrict__ mscr,
                                               float* __restrict__ dout,
                                               int NUn, int NMn) {
  int i = blockIdx.x * 256 + threadIdx.x;
  int stride = gridDim.x * 256;
  int nu8 = NUn * HDIM / 8;
  for (int j = i; j < nu8; j += stride) {
    uint4 v = *(const uint4*)&ubuf[(size_t)j * 8];
    float4 f0, f1;
    f0.x = __uint_as_float(v.x << 16); f0.y = __uint_as_float(v.x & 0xFFFF0000u);
    f0.z = __uint_as_float(v.y << 16); f0.w = __uint_as_float(v.y & 0xFFFF0000u);
    f1.x = __uint_as_float(v.z << 16); f1.y = __uint_as_float(v.z & 0xFFFF0000u);
    f1.z = __uint_as_float(v.w << 16); f1.w = __uint_as_float(v.w & 0xFFFF0000u);
    *(float4*)&dout[(size_t)j * 8] = f0;
    *(float4*)&dout[(size_t)j * 8 + 4] = f1;
  }
  float* m2 = dout + (size_t)NUn * HDIM;
  int nm4 = NMn * HDIM / 4;
  for (int j = i; j < nm4; j += stride) {
    *(float4*)&m2[(size_t)j * 4] = *(const float4*)&mscr[(size_t)j * 4];
  }
}

// ---------------- launch ----------------

static inline int imin(int a, int b) { return a < b ? a : b; }

extern "C" void kernel_launch(void* const* d_in, const int* in_sizes, int n_in,
                              void* d_out, int out_size, void* d_ws, size_t ws_size,
                              hipStream_t stream) {
  const int NU = in_sizes[0];
  const int NM = in_sizes[1];
  const int E  = in_sizes[2];

  const int* src_um = (const int*)d_in[2];
  const int* dst_um = (const int*)d_in[3];
  const float* user_table  = (const float*)d_in[6];
  const float* movie_table = (const float*)d_in[7];
  const float* Wl1_um = (const float*)d_in[8];
  const float* Wr1_um = (const float*)d_in[9];
  const float* Wl1_mu = (const float*)d_in[10];
  const float* Wr1_mu = (const float*)d_in[11];
  const float* Wl2_um = (const float*)d_in[12];
  const float* Wr2_um = (const float*)d_in[13];
  const float* Wl2_mu = (const float*)d_in[14];
  const float* Wr2_mu = (const float*)d_in[15];
  const float* b1_um = (const float*)d_in[16];
  const float* b1_mu = (const float*)d_in[17];
  const float* b2_um = (const float*)d_in[18];
  const float* b2_mu = (const float*)d_in[19];

  float* out_u2 = (float*)d_out;                       // [NU,64] fp32
  float* out_m2 = (float*)d_out + (size_t)NU * HDIM;   // [NM,64] fp32

  // workspace carve (256B aligned)
  char* ws = (char*)d_ws;
  size_t off = 0;
  auto carve = [&](size_t bytes) -> char* {
    char* p = ws + off;
    off = (off + bytes + 255) & ~(size_t)255;
    return p;
  };
  int* meta = (int*)carve((size_t)(NM + NU + 2) * 4);
  int* curm = meta;
  int* curu = meta + NM;
  int* ovfm_cnt = meta + NM + NU;
  int* ovfu_cnt = meta + NM + NU + 1;
  int nmeta = NM + NU + 2;
  int* ovfm = (int*)carve((size_t)OVF_MAX * 2 * 4);
  int* ovfu = (int*)carve((size_t)OVF_MAX * 2 * 4);
  int* bktm = (int*)carve((size_t)NM * CAP_M * 4);                        // user ids
  unsigned short* bktu = (unsigned short*)carve((size_t)NU * CAP_U * 2);  // movie ids
  unsigned short* mb = (unsigned short*)carve((size_t)NM * HDIM * 2);     // bf16 movie tbl
  unsigned short* ub = (unsigned short*)carve((size_t)NU * HDIM * 2);     // bf16 user tbl

  // path A (layer-1 outputs in ws) if it fits; else path B (in d_out + finalize)
  size_t m1sz = (((size_t)NM * HDIM * 2) + 255) & ~(size_t)255;
  size_t u1sz = (((size_t)NU * HDIM * 2) + 255) & ~(size_t)255;
  bool pathA = (off + m1sz + u1sz) <= ws_size;

  unsigned short *m1b, *u1b, *ubuf = 0;
  float* mscr = 0;
  if (pathA) {
    m1b = (unsigned short*)carve((size_t)NM * HDIM * 2);
    u1b = (unsigned short*)carve((size_t)NU * HDIM * 2);
  } else {
    u1b = (unsigned short*)d_out;                                   // [0, NU*128)
    m1b = (unsigned short*)((char*)d_out + (size_t)NU * 256);       // inside m2 region
    mscr = (float*)carve((size_t)NM * HDIM * 4);                    // m2 scratch fp32
    ubuf = ub;                                                      // ub dead after layer1
  }

  const int TB = 256;

  // 0) init + 1) fill
  int n8u = NU * HDIM / 8, n8m = NM * HDIM / 8;
  k_init<<<3072, TB, 0, stream>>>(meta, nmeta, user_table, ub, n8u,
                                  movie_table, mb, n8m);
  k_fillb2_x<<<2048, TB, 0, stream>>>(src_um, dst_um,
                                      curm, bktm, ovfm_cnt, ovfm,
                                      curu, bktu, ovfu_cnt, ovfu,
                                      E, NM, NU);

  int gM = (NM + 127) / 128;   // 8 waves x 16 nodes per block
  int gU = (NU + 127) / 128;

  // 2) layer 1 (relu): fused gather+MFMA, bf16 outputs
  k_sagex<int, 1><<<gM, 512, 0, stream>>>(ub, curm, bktm, CAP_M, ovfm_cnt, ovfm,
                                          mb, Wl1_um, Wr1_um, b1_um, m1b, NM, 1);
  k_sagex<unsigned short, 1><<<gU, 512, 0, stream>>>(mb, curu, bktu, CAP_U, ovfu_cnt, ovfu,
                                                     ub, Wl1_mu, Wr1_mu, b1_mu, u1b, NU, 1);
  k_redo<<<64, 128, 0, stream>>>(ovfm_cnt, ovfm, ub, curm, bktm, CAP_M, mb,
                                 Wl1_um, Wr1_um, b1_um, m1b, 1, 1,
                                 ovfu_cnt, ovfu, mb, curu, bktu, CAP_U, ub,
                                 Wl1_mu, Wr1_mu, b1_mu, u1b, 1, 1);

  // 3) layer 2 (no relu): redo first (sagex skips ovf rows), then fused convs
  void* m2dst = pathA ? (void*)out_m2 : (void*)mscr;
  void* u2dst = pathA ? (void*)out_u2 : (void*)ubuf;
  k_redo<<<64, 128, 0, stream>>>(ovfm_cnt, ovfm, u1b, curm, bktm, CAP_M, m1b,
                                 Wl2_um, Wr2_um, b2_um, m2dst, 0, 0,
                                 ovfu_cnt, ovfu, m1b, curu, bktu, CAP_U, u1b,
                                 Wl2_mu, Wr2_mu, b2_mu, u2dst, pathA ? 0 : 1, 0);
  if (pathA) {
    k_sagex<unsigned short, 0><<<gU, 512, 0, stream>>>(m1b, curu, bktu, CAP_U, ovfu_cnt, ovfu,
                                                       u1b, Wl2_mu, Wr2_mu, b2_mu,
                                                       out_u2, NU, 0);
    k_sagex<int, 0><<<gM, 512, 0, stream>>>(u1b, curm, bktm, CAP_M, ovfm_cnt, ovfm,
                                            m1b, Wl2_um, Wr2_um, b2_um,
                                            out_m2, NM, 0);
  } else {
    k_sagex<unsigned short, 1><<<gU, 512, 0, stream>>>(m1b, curu, bktu, CAP_U, ovfu_cnt, ovfu,
                                                       u1b, Wl2_mu, Wr2_mu, b2_mu,
                                                       ubuf, NU, 0);
    k_sagex<int, 0><<<gM, 512, 0, stream>>>(u1b, curm, bktm, CAP_M, ovfm_cnt, ovfm,
                                            m1b, Wl2_um, Wr2_um, b2_um,
                                            mscr, NM, 0);
    k_final<<<2048, TB, 0, stream>>>(ubuf, mscr, (float*)d_out, NU, NM);
  }
}

// Round 16
// 349.392 us; speedup vs baseline: 1.3656x; 1.3656x over previous
//
#include <hip/hip_runtime.h>

#define HDIM 64
#define CAP_M 96
#define CAP_U 32
#define OVF_MAX 65536
#define NBIN 512

typedef __attribute__((ext_vector_type(8))) short bf16x8;   // 8 bf16 (4 VGPRs)
typedef __attribute__((ext_vector_type(4))) float f32x4;    // 4 fp32

// ---------------- bf16 helpers ----------------
__device__ __forceinline__ float bf2f(unsigned short u) {
  unsigned int x = ((unsigned int)u) << 16;
  return __uint_as_float(x);
}
__device__ __forceinline__ unsigned short f2bf(float f) {
  unsigned int x = __float_as_uint(f);
  unsigned int r = (x + 0x7FFFu + ((x >> 16) & 1u)) >> 16;  // RNE
  return (unsigned short)r;
}

// ---------------- init: zero meta + bf16 table copies (r13 proven) ----------------
__global__ __launch_bounds__(256) void k_init(int* __restrict__ meta, int nmeta,
                                              const float* __restrict__ ut,
                                              unsigned short* __restrict__ ub, int n8u,
                                              const float* __restrict__ mt,
                                              unsigned short* __restrict__ mb, int n8m) {
  int bid = blockIdx.x;
  if (bid < 512) {
    int i = bid * 256 + threadIdx.x;
    for (int j = i; j < nmeta; j += 512 * 256) meta[j] = 0;
  } else if (bid < 512 + 2048) {
    int i = (bid - 512) * 256 + threadIdx.x;
    for (int j = i; j < n8u; j += 2048 * 256) {
      const float4* p = (const float4*)(ut + (size_t)j * 8);
      float4 a = p[0], b = p[1];
      uint4 o;
      o.x = (unsigned int)f2bf(a.x) | ((unsigned int)f2bf(a.y) << 16);
      o.y = (unsigned int)f2bf(a.z) | ((unsigned int)f2bf(a.w) << 16);
      o.z = (unsigned int)f2bf(b.x) | ((unsigned int)f2bf(b.y) << 16);
      o.w = (unsigned int)f2bf(b.z) | ((unsigned int)f2bf(b.w) << 16);
      *(uint4*)(ub + (size_t)j * 8) = o;
    }
  } else {
    int i = (bid - 512 - 2048) * 256 + threadIdx.x;
    for (int j = i; j < n8m; j += 512 * 256) {
      const float4* p = (const float4*)(mt + (size_t)j * 8);
      float4 a = p[0], b = p[1];
      uint4 o;
      o.x = (unsigned int)f2bf(a.x) | ((unsigned int)f2bf(a.y) << 16);
      o.y = (unsigned int)f2bf(a.z) | ((unsigned int)f2bf(a.w) << 16);
      o.z = (unsigned int)f2bf(b.x) | ((unsigned int)f2bf(b.y) << 16);
      o.w = (unsigned int)f2bf(b.z) | ((unsigned int)f2bf(b.w) << 16);
      *(uint4*)(mb + (size_t)j * 8) = o;
    }
  }
}

// ---------------- binned CSR build: NO global atomics on the hot path ----------------
// Phase 1: per-block 512-bin histogram (LDS atomics). gh[bin*512 + blk].
__global__ __launch_bounds__(256) void k_hist(const int* __restrict__ keys, int E, int Nd,
                                              int* __restrict__ gh) {
  __shared__ int h[NBIN];
  int t = threadIdx.x;
  h[t] = 0; h[t + 256] = 0;
  __syncthreads();
  int e4 = (E + 3) >> 2;
  int c4 = (e4 + NBIN - 1) >> 9;
  int clen = c4 << 2;
  int s = blockIdx.x * clen;
  int epos = s + clen; if (epos > E) epos = E;
  for (int i = s + 4 * t; i < epos; i += 1024) {
    int n = epos - i; if (n > 4) n = 4;
    if (n == 4) {
      int4 k4 = *(const int4*)&keys[i];
      atomicAdd(&h[(int)((long long)k4.x * NBIN / Nd)], 1);
      atomicAdd(&h[(int)((long long)k4.y * NBIN / Nd)], 1);
      atomicAdd(&h[(int)((long long)k4.z * NBIN / Nd)], 1);
      atomicAdd(&h[(int)((long long)k4.w * NBIN / Nd)], 1);
    } else {
      for (int j = 0; j < n; ++j)
        atomicAdd(&h[(int)((long long)keys[i + j] * NBIN / Nd)], 1);
    }
  }
  __syncthreads();
  gh[(size_t)t * NBIN + blockIdx.x] = h[t];
  gh[(size_t)(t + 256) * NBIN + blockIdx.x] = h[t + 256];
}

// scan kernels (r5-proven): chunk 1024/block
__global__ void k_block_sum(const int* __restrict__ in, int* __restrict__ part, int n) {
  __shared__ int s[256];
  int b = blockIdx.x, t = threadIdx.x;
  int base = b * 1024;
  int v = 0;
  for (int i = t; i < 1024; i += 256) {
    int idx = base + i;
    if (idx < n) v += in[idx];
  }
  s[t] = v;
  __syncthreads();
  for (int o = 128; o > 0; o >>= 1) {
    if (t < o) s[t] += s[t + o];
    __syncthreads();
  }
  if (t == 0) part[b] = s[0];
}

__global__ void k_scan_part(int* __restrict__ part, int nb) {
  __shared__ int s[256];
  int t = threadIdx.x;
  int v = (t < nb) ? part[t] : 0;
  s[t] = v;
  __syncthreads();
  for (int o = 1; o < 256; o <<= 1) {
    int u = (t >= o) ? s[t - o] : 0;
    __syncthreads();
    s[t] += u;
    __syncthreads();
  }
  if (t < nb) part[t] = s[t] - v;  // exclusive
}

__global__ void k_scan_final(const int* __restrict__ in, const int* __restrict__ part,
                             int* __restrict__ out, int n) {
  __shared__ int s[256];
  int b = blockIdx.x, t = threadIdx.x;
  int base = b * 1024 + t * 4;
  int a[4];
#pragma unroll
  for (int i = 0; i < 4; i++) a[i] = (base + i < n) ? in[base + i] : 0;
  int tsum = a[0] + a[1] + a[2] + a[3];
  s[t] = tsum;
  __syncthreads();
  for (int o = 1; o < 256; o <<= 1) {
    int u = (t >= o) ? s[t - o] : 0;
    __syncthreads();
    s[t] += u;
    __syncthreads();
  }
  int excl = s[t] - tsum + part[b];
#pragma unroll
  for (int i = 0; i < 4; i++) {
    if (base + i < n) out[base + i] = excl;
    excl += a[i];
  }
}

// Phase 2: scatter edges into bin-contiguous order (LDS cursors from scan)
__global__ __launch_bounds__(256) void k_scatter(const int* __restrict__ keys,
                                                 const int* __restrict__ vals,
                                                 int E, int Nd,
                                                 const int* __restrict__ offs,
                                                 int2* __restrict__ binned) {
  __shared__ int lcur[NBIN];
  int t = threadIdx.x;
  lcur[t] = offs[(size_t)t * NBIN + blockIdx.x];
  lcur[t + 256] = offs[(size_t)(t + 256) * NBIN + blockIdx.x];
  __syncthreads();
  int e4 = (E + 3) >> 2;
  int c4 = (e4 + NBIN - 1) >> 9;
  int clen = c4 << 2;
  int s = blockIdx.x * clen;
  int epos = s + clen; if (epos > E) epos = E;
  for (int i = s + 4 * t; i < epos; i += 1024) {
    int n = epos - i; if (n > 4) n = 4;
    if (n == 4) {
      int4 k4 = *(const int4*)&keys[i];
      int4 v4 = *(const int4*)&vals[i];
      int b0 = (int)((long long)k4.x * NBIN / Nd);
      int b1 = (int)((long long)k4.y * NBIN / Nd);
      int b2 = (int)((long long)k4.z * NBIN / Nd);
      int b3 = (int)((long long)k4.w * NBIN / Nd);
      int p0 = atomicAdd(&lcur[b0], 1);
      int p1 = atomicAdd(&lcur[b1], 1);
      int p2 = atomicAdd(&lcur[b2], 1);
      int p3 = atomicAdd(&lcur[b3], 1);
      binned[p0] = make_int2(k4.x, v4.x);
      binned[p1] = make_int2(k4.y, v4.y);
      binned[p2] = make_int2(k4.z, v4.z);
      binned[p3] = make_int2(k4.w, v4.w);
    } else {
      for (int j = 0; j < n; ++j) {
        int k = keys[i + j], v = vals[i + j];
        int bb = (int)((long long)k * NBIN / Nd);
        int p = atomicAdd(&lcur[bb], 1);
        binned[p] = make_int2(k, v);
      }
    }
  }
}

// Phase 3: one block per bin; cursors for the bin's <=391 dsts live in LDS.
// slot via LDS atomic; bucket writes land in a ~30KB window. Degrees written once.
template <typename IT>
__global__ __launch_bounds__(256) void k_fillbin(const int2* __restrict__ binned,
                                                 const int* __restrict__ offs,
                                                 int E, int Nd, int cap,
                                                 IT* __restrict__ bkt,
                                                 int* __restrict__ cur,
                                                 int* __restrict__ ovf_cnt,
                                                 int* __restrict__ ovf) {
  __shared__ int lcur[400];
  int b = blockIdx.x;
  int t = threadIdx.x;
  int lo = (int)(((long long)b * Nd + NBIN - 1) >> 9);
  int hi = (int)(((long long)(b + 1) * Nd + NBIN - 1) >> 9);
  int width = hi - lo;
  for (int i = t; i < width; i += 256) lcur[i] = 0;
  __syncthreads();
  int start = offs[b << 9];
  int end = (b == NBIN - 1) ? E : offs[(b + 1) << 9];
  for (int i = start + t; i < end; i += 256) {
    int2 p = binned[i];
    int li = p.x - lo;
    int pos = atomicAdd(&lcur[li], 1);
    if (pos < cap) bkt[(size_t)p.x * cap + pos] = (IT)p.y;
    else { int q = atomicAdd(ovf_cnt, 1); if (q < OVF_MAX) { ovf[2 * q] = p.x; ovf[2 * q + 1] = p.y; } }
  }
  __syncthreads();
  for (int i = t; i < width; i += 256) cur[lo + i] = lcur[i];
}

// ---------------- aggregation: 8 lanes/node, 16B uint4 loads (r13 proven) ----------------
__device__ __forceinline__ void acc8(float4& a, float4& b, uint4 w) {
  a.x += __uint_as_float(w.x << 16);
  a.y += __uint_as_float(w.x & 0xFFFF0000u);
  a.z += __uint_as_float(w.y << 16);
  a.w += __uint_as_float(w.y & 0xFFFF0000u);
  b.x += __uint_as_float(w.z << 16);
  b.y += __uint_as_float(w.z & 0xFFFF0000u);
  b.z += __uint_as_float(w.w << 16);
  b.w += __uint_as_float(w.w & 0xFFFF0000u);
}

template <typename IT>
__global__ __launch_bounds__(256) void k_agg8(const unsigned short* __restrict__ xb,
                                              const int* __restrict__ cur,
                                              const IT* __restrict__ bkt,
                                              int cap,
                                              float* __restrict__ agg,
                                              int n_dst) {
  int t = threadIdx.x;
  int q = t & 7;
  int gg = (blockIdx.x * 256 + t) >> 3;
  int stride = (gridDim.x * 256) >> 3;

  for (int node = gg; node < n_dst; node += stride) {
    int deg = cur[node];
    int nb = deg < cap ? deg : cap;
    const IT* lst = bkt + (size_t)node * cap;
    float4 a = make_float4(0.f, 0.f, 0.f, 0.f);
    float4 b = a;
    int e = 0;
    for (; e + 4 <= nb; e += 4) {
      int i0, i1, i2, i3;
      if (sizeof(IT) == 2) {
        ushort4 ia = *(const ushort4*)&lst[e];
        i0 = ia.x; i1 = ia.y; i2 = ia.z; i3 = ia.w;
      } else {
        int4 ia = *(const int4*)&lst[e];
        i0 = ia.x; i1 = ia.y; i2 = ia.z; i3 = ia.w;
      }
      uint4 w0 = *(const uint4*)&xb[(size_t)i0 * HDIM + 8 * q];
      uint4 w1 = *(const uint4*)&xb[(size_t)i1 * HDIM + 8 * q];
      uint4 w2 = *(const uint4*)&xb[(size_t)i2 * HDIM + 8 * q];
      uint4 w3 = *(const uint4*)&xb[(size_t)i3 * HDIM + 8 * q];
      acc8(a, b, w0);
      acc8(a, b, w1);
      acc8(a, b, w2);
      acc8(a, b, w3);
    }
    for (; e < nb; ++e) {
      uint4 w0 = *(const uint4*)&xb[(size_t)lst[e] * HDIM + 8 * q];
      acc8(a, b, w0);
    }
    float inv = deg > 0 ? 1.f / (float)deg : 0.f;
    a.x *= inv; a.y *= inv; a.z *= inv; a.w *= inv;
    b.x *= inv; b.y *= inv; b.z *= inv; b.w *= inv;
    *(float4*)&agg[(size_t)node * HDIM + 8 * q] = a;
    *(float4*)&agg[(size_t)node * HDIM + 8 * q + 4] = b;
  }
}

// ---------------- overflow fixup (combined; normally a no-op) ----------------
__device__ __forceinline__ void fix_body(const int* __restrict__ cnt_p,
                                         const int* __restrict__ ovf,
                                         const unsigned short* __restrict__ xb,
                                         const int* __restrict__ cur,
                                         float* __restrict__ agg,
                                         int bid, int nblk) {
  int n = *cnt_p;
  if (n > OVF_MAX) n = OVF_MAX;
  int tid = bid * 256 + threadIdx.x;
  int q = tid & 15;
  int p = tid >> 4;
  int stride = (nblk * 256) >> 4;
  for (; p < n; p += stride) {
    int d = ovf[2 * p];
    int s = ovf[2 * p + 1];
    float inv = 1.f / (float)cur[d];
    ushort4 v = *(const ushort4*)&xb[(size_t)s * HDIM + 4 * q];
    atomicAdd(&agg[(size_t)d * HDIM + 4 * q + 0], bf2f(v.x) * inv);
    atomicAdd(&agg[(size_t)d * HDIM + 4 * q + 1], bf2f(v.y) * inv);
    atomicAdd(&agg[(size_t)d * HDIM + 4 * q + 2], bf2f(v.z) * inv);
    atomicAdd(&agg[(size_t)d * HDIM + 4 * q + 3], bf2f(v.w) * inv);
  }
}

__global__ __launch_bounds__(256) void k_fix2(const int* __restrict__ cntM,
                                              const int* __restrict__ ovfM,
                                              const unsigned short* __restrict__ xbM,
                                              const int* __restrict__ curM,
                                              float* __restrict__ aggM,
                                              const int* __restrict__ cntU,
                                              const int* __restrict__ ovfU,
                                              const unsigned short* __restrict__ xbU,
                                              const int* __restrict__ curU,
                                              float* __restrict__ aggU) {
  if (blockIdx.x < 16) fix_body(cntM, ovfM, xbM, curM, aggM, blockIdx.x, 16);
  else                 fix_body(cntU, ovfU, xbU, curU, aggU, blockIdx.x - 16, 16);
}

// ---------------- MFMA transform (r13 proven): out = [agg|X] @ [Wl;Wr] + b ----------------
template <int OUTBF>
__global__ __launch_bounds__(256) void k_xmfma(const float* A,
                                               const unsigned short* X,
                                               const float* __restrict__ Wl,
                                               const float* __restrict__ Wr,
                                               const float* __restrict__ bias,
                                               void* outv,
                                               int n_dst, int do_relu) {
  __shared__ unsigned short sWt[64][136];  // W^T bf16, padded
  __shared__ float sOut[4][16][68];        // per-wave C staging

  int t = threadIdx.x;
  for (int id = t; id < 64 * 128; id += 256) {
    int col = id & 63;
    int k = id >> 6;
    float wv = (k < 64) ? Wl[k * 64 + col] : Wr[(k - 64) * 64 + col];
    sWt[col][k] = f2bf(wv);
  }
  __syncthreads();

  int w = t >> 6;
  int l = t & 63;
  int lm = l & 15;
  int lg = l >> 4;
  int wid = blockIdx.x * 4 + w;
  int nw = gridDim.x * 4;
  int ntiles = (n_dst + 15) >> 4;

  for (int tile = wid; tile < ntiles; tile += nw) {
    int nbase = tile << 4;
    int row = nbase + lm;
    int rowc = row < n_dst ? row : (n_dst - 1);

    bf16x8 afr[4];
    const float* ar = A + (size_t)rowc * HDIM;
#pragma unroll
    for (int s = 0; s < 2; ++s) {
      float4 f0 = *(const float4*)(ar + 32 * s + 8 * lg);
      float4 f1 = *(const float4*)(ar + 32 * s + 8 * lg + 4);
      bf16x8 v;
      v[0] = (short)f2bf(f0.x); v[1] = (short)f2bf(f0.y);
      v[2] = (short)f2bf(f0.z); v[3] = (short)f2bf(f0.w);
      v[4] = (short)f2bf(f1.x); v[5] = (short)f2bf(f1.y);
      v[6] = (short)f2bf(f1.z); v[7] = (short)f2bf(f1.w);
      afr[s] = v;
    }
    const unsigned short* xr = X + (size_t)rowc * HDIM;
#pragma unroll
    for (int s = 0; s < 2; ++s) {
      afr[2 + s] = *(const bf16x8*)(xr + 32 * s + 8 * lg);
    }

    f32x4 zz = {0.f, 0.f, 0.f, 0.f};
    f32x4 acc[4];
#pragma unroll
    for (int n = 0; n < 4; ++n) acc[n] = zz;
#pragma unroll
    for (int s = 0; s < 4; ++s) {
#pragma unroll
      for (int n = 0; n < 4; ++n) {
        bf16x8 bfr = *(const bf16x8*)(&sWt[16 * n + lm][32 * s + 8 * lg]);
        acc[n] = __builtin_amdgcn_mfma_f32_16x16x32_bf16(afr[s], bfr, acc[n], 0, 0, 0);
      }
    }

#pragma unroll
    for (int n = 0; n < 4; ++n) {
      float bj = bias[16 * n + lm];
#pragma unroll
      for (int r = 0; r < 4; ++r) {
        float v = acc[n][r] + bj;
        if (do_relu) v = fmaxf(v, 0.f);
        sOut[w][lg * 4 + r][16 * n + lm] = v;
      }
    }

    int node = nbase + (l >> 2);
    if (node < n_dst) {
      int c0 = (l & 3) * 16;
      float4 o0 = *(const float4*)&sOut[w][l >> 2][c0];
      float4 o1 = *(const float4*)&sOut[w][l >> 2][c0 + 4];
      float4 o2 = *(const float4*)&sOut[w][l >> 2][c0 + 8];
      float4 o3 = *(const float4*)&sOut[w][l >> 2][c0 + 12];
      if (OUTBF) {
        unsigned short* ob = (unsigned short*)outv;
        uint4 p0, p1;
        p0.x = (unsigned int)f2bf(o0.x) | ((unsigned int)f2bf(o0.y) << 16);
        p0.y = (unsigned int)f2bf(o0.z) | ((unsigned int)f2bf(o0.w) << 16);
        p0.z = (unsigned int)f2bf(o1.x) | ((unsigned int)f2bf(o1.y) << 16);
        p0.w = (unsigned int)f2bf(o1.z) | ((unsigned int)f2bf(o1.w) << 16);
        p1.x = (unsigned int)f2bf(o2.x) | ((unsigned int)f2bf(o2.y) << 16);
        p1.y = (unsigned int)f2bf(o2.z) | ((unsigned int)f2bf(o2.w) << 16);
        p1.z = (unsigned int)f2bf(o3.x) | ((unsigned int)f2bf(o3.y) << 16);
        p1.w = (unsigned int)f2bf(o3.z) | ((unsigned int)f2bf(o3.w) << 16);
        *(uint4*)&ob[(size_t)node * HDIM + c0] = p0;
        *(uint4*)&ob[(size_t)node * HDIM + c0 + 8] = p1;
      } else {
        float* of = (float*)outv;
        *(float4*)&of[(size_t)node * HDIM + c0] = o0;
        *(float4*)&of[(size_t)node * HDIM + c0 + 4] = o1;
        *(float4*)&of[(size_t)node * HDIM + c0 + 8] = o2;
        *(float4*)&of[(size_t)node * HDIM + c0 + 12] = o3;
      }
    }
  }
}

// ---------------- launch ----------------

static inline int imin(int a, int b) { return a < b ? a : b; }

extern "C" void kernel_launch(void* const* d_in, const int* in_sizes, int n_in,
                              void* d_out, int out_size, void* d_ws, size_t ws_size,
                              hipStream_t stream) {
  const int NU = in_sizes[0];
  const int NM = in_sizes[1];
  const int E  = in_sizes[2];

  const int* src_um = (const int*)d_in[2];
  const int* dst_um = (const int*)d_in[3];
  const float* user_table  = (const float*)d_in[6];
  const float* movie_table = (const float*)d_in[7];
  const float* Wl1_um = (const float*)d_in[8];
  const float* Wr1_um = (const float*)d_in[9];
  const float* Wl1_mu = (const float*)d_in[10];
  const float* Wr1_mu = (const float*)d_in[11];
  const float* Wl2_um = (const float*)d_in[12];
  const float* Wr2_um = (const float*)d_in[13];
  const float* Wl2_mu = (const float*)d_in[14];
  const float* Wr2_mu = (const float*)d_in[15];
  const float* b1_um = (const float*)d_in[16];
  const float* b1_mu = (const float*)d_in[17];
  const float* b2_um = (const float*)d_in[18];
  const float* b2_mu = (const float*)d_in[19];

  float* out_u2 = (float*)d_out;                       // [NU,64]
  float* out_m2 = (float*)d_out + (size_t)NU * HDIM;   // [NM,64]
  float* aggu = out_u2;   // agg scratch in d_out; layer2 xform in-place per-row
  float* aggm = out_m2;
  // binned edge scratch also lives in d_out (dead before aggs run)
  int2* binned = (int2*)d_out;   // E*8 = 16MB << out bytes

  // workspace carve (256B aligned); total ~63 MB
  char* ws = (char*)d_ws;
  size_t off = 0;
  auto carve = [&](size_t bytes) -> char* {
    char* p = ws + off;
    off = (off + bytes + 255) & ~(size_t)255;
    return p;
  };
  int* meta = (int*)carve((size_t)(NM + NU + 2) * 4);
  int* curm = meta;
  int* curu = meta + NM;
  int* ovfm_cnt = meta + NM + NU;
  int* ovfu_cnt = meta + NM + NU + 1;
  int nmeta = NM + NU + 2;
  int* ovfm = (int*)carve((size_t)OVF_MAX * 2 * 4);
  int* ovfu = (int*)carve((size_t)OVF_MAX * 2 * 4);
  int* bktm = (int*)carve((size_t)NM * CAP_M * 4);                        // user ids (int)
  unsigned short* bktu = (unsigned short*)carve((size_t)NU * CAP_U * 2);  // movie ids (ushort)
  unsigned short* mb = (unsigned short*)carve((size_t)NM * HDIM * 2);     // bf16 movie tbl -> m1
  unsigned short* ub = (unsigned short*)carve((size_t)NU * HDIM * 2);     // bf16 user tbl -> u1
  int* gh  = (int*)carve((size_t)NBIN * NBIN * 4);   // histograms 1MB
  int* ghs = (int*)carve((size_t)NBIN * NBIN * 4);   // scanned    1MB
  int* part = (int*)carve(256 * 4);
  (void)ws_size;

  const int TB = 256;
  int nscan = NBIN * NBIN;             // 262144
  int nbscan = (nscan + 1023) / 1024;  // 256

  // 0) init: zero counters + bf16 table copies
  int n8u = NU * HDIM / 8, n8m = NM * HDIM / 8;
  k_init<<<3072, TB, 0, stream>>>(meta, nmeta, user_table, ub, n8u,
                                  movie_table, mb, n8m);

  // 1) binned CSR build, direction M (keys=dst_um, vals=src_um)
  k_hist<<<NBIN, TB, 0, stream>>>(dst_um, E, NM, gh);
  k_block_sum<<<nbscan, TB, 0, stream>>>(gh, part, nscan);
  k_scan_part<<<1, TB, 0, stream>>>(part, nbscan);
  k_scan_final<<<nbscan, TB, 0, stream>>>(gh, part, ghs, nscan);
  k_scatter<<<NBIN, TB, 0, stream>>>(dst_um, src_um, E, NM, ghs, binned);
  k_fillbin<int><<<NBIN, TB, 0, stream>>>(binned, ghs, E, NM, CAP_M,
                                          bktm, curm, ovfm_cnt, ovfm);

  // 2) binned CSR build, direction U (keys=src_um, vals=dst_um)
  k_hist<<<NBIN, TB, 0, stream>>>(src_um, E, NU, gh);
  k_block_sum<<<nbscan, TB, 0, stream>>>(gh, part, nscan);
  k_scan_part<<<1, TB, 0, stream>>>(part, nbscan);
  k_scan_final<<<nbscan, TB, 0, stream>>>(gh, part, ghs, nscan);
  k_scatter<<<NBIN, TB, 0, stream>>>(src_um, dst_um, E, NU, ghs, binned);
  k_fillbin<unsigned short><<<NBIN, TB, 0, stream>>>(binned, ghs, E, NU, CAP_U,
                                                     bktu, curu, ovfu_cnt, ovfu);

  int gAm = imin((NM + 31) / 32, 8192);
  int gAu = imin((NU + 31) / 32, 8192);
  int gXm = (NM + 63) / 64;   // 64 nodes/block (4 waves x 16)
  int gXu = (NU + 63) / 64;

  // 3) layer 1 (relu): serial aggs (r9 lesson), fix, MFMA xforms (in-place bf16)
  k_agg8<int><<<gAm, TB, 0, stream>>>(ub, curm, bktm, CAP_M, aggm, NM);
  k_agg8<unsigned short><<<gAu, TB, 0, stream>>>(mb, curu, bktu, CAP_U, aggu, NU);
  k_fix2<<<32, TB, 0, stream>>>(ovfm_cnt, ovfm, ub, curm, aggm,
                                ovfu_cnt, ovfu, mb, curu, aggu);
  k_xmfma<1><<<gXm, TB, 0, stream>>>(aggm, mb, Wl1_um, Wr1_um, b1_um,
                                     mb, NM, 1);   // mb becomes m1 (bf16)
  k_xmfma<1><<<gXu, TB, 0, stream>>>(aggu, ub, Wl1_mu, Wr1_mu, b1_mu,
                                     ub, NU, 1);   // ub becomes u1 (bf16)

  // 4) layer 2 (no relu): aggs into d_out, MFMA xforms in-place -> fp32 out
  k_agg8<int><<<gAm, TB, 0, stream>>>(ub, curm, bktm, CAP_M, aggm, NM);
  k_agg8<unsigned short><<<gAu, TB, 0, stream>>>(mb, curu, bktu, CAP_U, aggu, NU);
  k_fix2<<<32, TB, 0, stream>>>(ovfm_cnt, ovfm, ub, curm, aggm,
                                ovfu_cnt, ovfu, mb, curu, aggu);
  k_xmfma<0><<<gXm, TB, 0, stream>>>(aggm, mb, Wl2_um, Wr2_um, b2_um,
                                     out_m2, NM, 0);
  k_xmfma<0><<<gXu, TB, 0, stream>>>(aggu, ub, Wl2_mu, Wr2_mu, b2_mu,
                                     out_u2, NU, 0);
}

// Round 17
// 347.006 us; speedup vs baseline: 1.3750x; 1.0069x over previous
//
#include <hip/hip_runtime.h>

#define HDIM 64
#define CAP_M 96
#define CAP_U 32
#define OVF_MAX 65536
#define NBIN 512

typedef __attribute__((ext_vector_type(8))) short bf16x8;   // 8 bf16 (4 VGPRs)
typedef __attribute__((ext_vector_type(4))) float f32x4;    // 4 fp32

// ---------------- bf16 helpers ----------------
__device__ __forceinline__ float bf2f(unsigned short u) {
  unsigned int x = ((unsigned int)u) << 16;
  return __uint_as_float(x);
}
__device__ __forceinline__ unsigned short f2bf(float f) {
  unsigned int x = __float_as_uint(f);
  unsigned int r = (x + 0x7FFFu + ((x >> 16) & 1u)) >> 16;  // RNE
  return (unsigned short)r;
}

// ---------------- init: zero meta + bf16 table copies (r13 proven) ----------------
__global__ __launch_bounds__(256) void k_init(int* __restrict__ meta, int nmeta,
                                              const float* __restrict__ ut,
                                              unsigned short* __restrict__ ub, int n8u,
                                              const float* __restrict__ mt,
                                              unsigned short* __restrict__ mb, int n8m) {
  int bid = blockIdx.x;
  if (bid < 512) {
    int i = bid * 256 + threadIdx.x;
    for (int j = i; j < nmeta; j += 512 * 256) meta[j] = 0;
  } else if (bid < 512 + 2048) {
    int i = (bid - 512) * 256 + threadIdx.x;
    for (int j = i; j < n8u; j += 2048 * 256) {
      const float4* p = (const float4*)(ut + (size_t)j * 8);
      float4 a = p[0], b = p[1];
      uint4 o;
      o.x = (unsigned int)f2bf(a.x) | ((unsigned int)f2bf(a.y) << 16);
      o.y = (unsigned int)f2bf(a.z) | ((unsigned int)f2bf(a.w) << 16);
      o.z = (unsigned int)f2bf(b.x) | ((unsigned int)f2bf(b.y) << 16);
      o.w = (unsigned int)f2bf(b.z) | ((unsigned int)f2bf(b.w) << 16);
      *(uint4*)(ub + (size_t)j * 8) = o;
    }
  } else {
    int i = (bid - 512 - 2048) * 256 + threadIdx.x;
    for (int j = i; j < n8m; j += 512 * 256) {
      const float4* p = (const float4*)(mt + (size_t)j * 8);
      float4 a = p[0], b = p[1];
      uint4 o;
      o.x = (unsigned int)f2bf(a.x) | ((unsigned int)f2bf(a.y) << 16);
      o.y = (unsigned int)f2bf(a.z) | ((unsigned int)f2bf(a.w) << 16);
      o.z = (unsigned int)f2bf(b.x) | ((unsigned int)f2bf(b.y) << 16);
      o.w = (unsigned int)f2bf(b.z) | ((unsigned int)f2bf(b.w) << 16);
      *(uint4*)(mb + (size_t)j * 8) = o;
    }
  }
}

// ---------------- binned CSR build: NO global atomics on the hot path ----------------
// Phase 1 (fused): per-block 512-bin histograms for BOTH directions in one
// edge pass. ghM[bin*512+blk], ghU[bin*512+blk].
__global__ __launch_bounds__(256) void k_hist2(const int* __restrict__ srcU,
                                               const int* __restrict__ dstM,
                                               int E, int NMd, int NUd,
                                               int* __restrict__ ghM,
                                               int* __restrict__ ghU) {
  __shared__ int hM[NBIN];
  __shared__ int hU[NBIN];
  int t = threadIdx.x;
  hM[t] = 0; hM[t + 256] = 0;
  hU[t] = 0; hU[t + 256] = 0;
  __syncthreads();
  int e4 = (E + 3) >> 2;
  int c4 = (e4 + NBIN - 1) >> 9;
  int clen = c4 << 2;
  int s = blockIdx.x * clen;
  int epos = s + clen; if (epos > E) epos = E;
  for (int i = s + 4 * t; i < epos; i += 1024) {
    int n = epos - i; if (n > 4) n = 4;
    if (n == 4) {
      int4 d4 = *(const int4*)&dstM[i];
      int4 s4 = *(const int4*)&srcU[i];
      atomicAdd(&hM[(int)((long long)d4.x * NBIN / NMd)], 1);
      atomicAdd(&hM[(int)((long long)d4.y * NBIN / NMd)], 1);
      atomicAdd(&hM[(int)((long long)d4.z * NBIN / NMd)], 1);
      atomicAdd(&hM[(int)((long long)d4.w * NBIN / NMd)], 1);
      atomicAdd(&hU[(int)((long long)s4.x * NBIN / NUd)], 1);
      atomicAdd(&hU[(int)((long long)s4.y * NBIN / NUd)], 1);
      atomicAdd(&hU[(int)((long long)s4.z * NBIN / NUd)], 1);
      atomicAdd(&hU[(int)((long long)s4.w * NBIN / NUd)], 1);
    } else {
      for (int j = 0; j < n; ++j) {
        atomicAdd(&hM[(int)((long long)dstM[i + j] * NBIN / NMd)], 1);
        atomicAdd(&hU[(int)((long long)srcU[i + j] * NBIN / NUd)], 1);
      }
    }
  }
  __syncthreads();
  ghM[(size_t)t * NBIN + blockIdx.x] = hM[t];
  ghM[(size_t)(t + 256) * NBIN + blockIdx.x] = hM[t + 256];
  ghU[(size_t)t * NBIN + blockIdx.x] = hU[t];
  ghU[(size_t)(t + 256) * NBIN + blockIdx.x] = hU[t + 256];
}

// scan kernels (r5-proven): chunk 1024/block
__global__ void k_block_sum(const int* __restrict__ in, int* __restrict__ part, int n) {
  __shared__ int s[256];
  int b = blockIdx.x, t = threadIdx.x;
  int base = b * 1024;
  int v = 0;
  for (int i = t; i < 1024; i += 256) {
    int idx = base + i;
    if (idx < n) v += in[idx];
  }
  s[t] = v;
  __syncthreads();
  for (int o = 128; o > 0; o >>= 1) {
    if (t < o) s[t] += s[t + o];
    __syncthreads();
  }
  if (t == 0) part[b] = s[0];
}

__global__ void k_scan_part(int* __restrict__ part, int nb) {
  __shared__ int s[256];
  int t = threadIdx.x;
  int v = (t < nb) ? part[t] : 0;
  s[t] = v;
  __syncthreads();
  for (int o = 1; o < 256; o <<= 1) {
    int u = (t >= o) ? s[t - o] : 0;
    __syncthreads();
    s[t] += u;
    __syncthreads();
  }
  if (t < nb) part[t] = s[t] - v;  // exclusive
}

__global__ void k_scan_final(const int* __restrict__ in, const int* __restrict__ part,
                             int* __restrict__ out, int n) {
  __shared__ int s[256];
  int b = blockIdx.x, t = threadIdx.x;
  int base = b * 1024 + t * 4;
  int a[4];
#pragma unroll
  for (int i = 0; i < 4; i++) a[i] = (base + i < n) ? in[base + i] : 0;
  int tsum = a[0] + a[1] + a[2] + a[3];
  s[t] = tsum;
  __syncthreads();
  for (int o = 1; o < 256; o <<= 1) {
    int u = (t >= o) ? s[t - o] : 0;
    __syncthreads();
    s[t] += u;
    __syncthreads();
  }
  int excl = s[t] - tsum + part[b];
#pragma unroll
  for (int i = 0; i < 4; i++) {
    if (base + i < n) out[base + i] = excl;
    excl += a[i];
  }
}

// Phase 2 (fused): scatter BOTH directions in one edge pass (LDS cursors).
__global__ __launch_bounds__(256) void k_scatter2(const int* __restrict__ srcU,
                                                  const int* __restrict__ dstM,
                                                  int E, int NMd, int NUd,
                                                  const int* __restrict__ offsM,
                                                  const int* __restrict__ offsU,
                                                  int2* __restrict__ binnedM,
                                                  int2* __restrict__ binnedU) {
  __shared__ int lcM[NBIN];
  __shared__ int lcU[NBIN];
  int t = threadIdx.x;
  lcM[t] = offsM[(size_t)t * NBIN + blockIdx.x];
  lcM[t + 256] = offsM[(size_t)(t + 256) * NBIN + blockIdx.x];
  lcU[t] = offsU[(size_t)t * NBIN + blockIdx.x];
  lcU[t + 256] = offsU[(size_t)(t + 256) * NBIN + blockIdx.x];
  __syncthreads();
  int e4 = (E + 3) >> 2;
  int c4 = (e4 + NBIN - 1) >> 9;
  int clen = c4 << 2;
  int s = blockIdx.x * clen;
  int epos = s + clen; if (epos > E) epos = E;
  for (int i = s + 4 * t; i < epos; i += 1024) {
    int n = epos - i; if (n > 4) n = 4;
    if (n == 4) {
      int4 d4 = *(const int4*)&dstM[i];
      int4 s4 = *(const int4*)&srcU[i];
      int bm0 = (int)((long long)d4.x * NBIN / NMd);
      int bm1 = (int)((long long)d4.y * NBIN / NMd);
      int bm2 = (int)((long long)d4.z * NBIN / NMd);
      int bm3 = (int)((long long)d4.w * NBIN / NMd);
      int pm0 = atomicAdd(&lcM[bm0], 1);
      int pm1 = atomicAdd(&lcM[bm1], 1);
      int pm2 = atomicAdd(&lcM[bm2], 1);
      int pm3 = atomicAdd(&lcM[bm3], 1);
      binnedM[pm0] = make_int2(d4.x, s4.x);
      binnedM[pm1] = make_int2(d4.y, s4.y);
      binnedM[pm2] = make_int2(d4.z, s4.z);
      binnedM[pm3] = make_int2(d4.w, s4.w);
      int bu0 = (int)((long long)s4.x * NBIN / NUd);
      int bu1 = (int)((long long)s4.y * NBIN / NUd);
      int bu2 = (int)((long long)s4.z * NBIN / NUd);
      int bu3 = (int)((long long)s4.w * NBIN / NUd);
      int pu0 = atomicAdd(&lcU[bu0], 1);
      int pu1 = atomicAdd(&lcU[bu1], 1);
      int pu2 = atomicAdd(&lcU[bu2], 1);
      int pu3 = atomicAdd(&lcU[bu3], 1);
      binnedU[pu0] = make_int2(s4.x, d4.x);
      binnedU[pu1] = make_int2(s4.y, d4.y);
      binnedU[pu2] = make_int2(s4.z, d4.z);
      binnedU[pu3] = make_int2(s4.w, d4.w);
    } else {
      for (int j = 0; j < n; ++j) {
        int dd = dstM[i + j], ss = srcU[i + j];
        int bm = (int)((long long)dd * NBIN / NMd);
        int pm = atomicAdd(&lcM[bm], 1);
        binnedM[pm] = make_int2(dd, ss);
        int bu = (int)((long long)ss * NBIN / NUd);
        int pu = atomicAdd(&lcU[bu], 1);
        binnedU[pu] = make_int2(ss, dd);
      }
    }
  }
}

// Phase 3: one block per bin; cursors for the bin's <=391 dsts live in LDS.
template <typename IT>
__global__ __launch_bounds__(256) void k_fillbin(const int2* __restrict__ binned,
                                                 const int* __restrict__ offs,
                                                 int E, int Nd, int cap,
                                                 IT* __restrict__ bkt,
                                                 int* __restrict__ cur,
                                                 int* __restrict__ ovf_cnt,
                                                 int* __restrict__ ovf) {
  __shared__ int lcur[400];
  int b = blockIdx.x;
  int t = threadIdx.x;
  int lo = (int)(((long long)b * Nd + NBIN - 1) >> 9);
  int hi = (int)(((long long)(b + 1) * Nd + NBIN - 1) >> 9);
  int width = hi - lo;
  for (int i = t; i < width; i += 256) lcur[i] = 0;
  __syncthreads();
  int start = offs[b << 9];
  int end = (b == NBIN - 1) ? E : offs[(b + 1) << 9];
  for (int i = start + t; i < end; i += 256) {
    int2 p = binned[i];
    int li = p.x - lo;
    int pos = atomicAdd(&lcur[li], 1);
    if (pos < cap) bkt[(size_t)p.x * cap + pos] = (IT)p.y;
    else { int q = atomicAdd(ovf_cnt, 1); if (q < OVF_MAX) { ovf[2 * q] = p.x; ovf[2 * q + 1] = p.y; } }
  }
  __syncthreads();
  for (int i = t; i < width; i += 256) cur[lo + i] = lcur[i];
}

// ---------------- aggregation: 8 lanes/node, 16B uint4 loads (r13 proven) ----------------
__device__ __forceinline__ void acc8(float4& a, float4& b, uint4 w) {
  a.x += __uint_as_float(w.x << 16);
  a.y += __uint_as_float(w.x & 0xFFFF0000u);
  a.z += __uint_as_float(w.y << 16);
  a.w += __uint_as_float(w.y & 0xFFFF0000u);
  b.x += __uint_as_float(w.z << 16);
  b.y += __uint_as_float(w.z & 0xFFFF0000u);
  b.z += __uint_as_float(w.w << 16);
  b.w += __uint_as_float(w.w & 0xFFFF0000u);
}

template <typename IT>
__global__ __launch_bounds__(256) void k_agg8(const unsigned short* __restrict__ xb,
                                              const int* __restrict__ cur,
                                              const IT* __restrict__ bkt,
                                              int cap,
                                              float* __restrict__ agg,
                                              int n_dst) {
  int t = threadIdx.x;
  int q = t & 7;
  int gg = (blockIdx.x * 256 + t) >> 3;
  int stride = (gridDim.x * 256) >> 3;

  for (int node = gg; node < n_dst; node += stride) {
    int deg = cur[node];
    int nb = deg < cap ? deg : cap;
    const IT* lst = bkt + (size_t)node * cap;
    float4 a = make_float4(0.f, 0.f, 0.f, 0.f);
    float4 b = a;
    int e = 0;
    for (; e + 4 <= nb; e += 4) {
      int i0, i1, i2, i3;
      if (sizeof(IT) == 2) {
        ushort4 ia = *(const ushort4*)&lst[e];
        i0 = ia.x; i1 = ia.y; i2 = ia.z; i3 = ia.w;
      } else {
        int4 ia = *(const int4*)&lst[e];
        i0 = ia.x; i1 = ia.y; i2 = ia.z; i3 = ia.w;
      }
      uint4 w0 = *(const uint4*)&xb[(size_t)i0 * HDIM + 8 * q];
      uint4 w1 = *(const uint4*)&xb[(size_t)i1 * HDIM + 8 * q];
      uint4 w2 = *(const uint4*)&xb[(size_t)i2 * HDIM + 8 * q];
      uint4 w3 = *(const uint4*)&xb[(size_t)i3 * HDIM + 8 * q];
      acc8(a, b, w0);
      acc8(a, b, w1);
      acc8(a, b, w2);
      acc8(a, b, w3);
    }
    for (; e < nb; ++e) {
      uint4 w0 = *(const uint4*)&xb[(size_t)lst[e] * HDIM + 8 * q];
      acc8(a, b, w0);
    }
    float inv = deg > 0 ? 1.f / (float)deg : 0.f;
    a.x *= inv; a.y *= inv; a.z *= inv; a.w *= inv;
    b.x *= inv; b.y *= inv; b.z *= inv; b.w *= inv;
    *(float4*)&agg[(size_t)node * HDIM + 8 * q] = a;
    *(float4*)&agg[(size_t)node * HDIM + 8 * q + 4] = b;
  }
}

// ---------------- overflow fixup (combined; normally a no-op) ----------------
__device__ __forceinline__ void fix_body(const int* __restrict__ cnt_p,
                                         const int* __restrict__ ovf,
                                         const unsigned short* __restrict__ xb,
                                         const int* __restrict__ cur,
                                         float* __restrict__ agg,
                                         int bid, int nblk) {
  int n = *cnt_p;
  if (n > OVF_MAX) n = OVF_MAX;
  int tid = bid * 256 + threadIdx.x;
  int q = tid & 15;
  int p = tid >> 4;
  int stride = (nblk * 256) >> 4;
  for (; p < n; p += stride) {
    int d = ovf[2 * p];
    int s = ovf[2 * p + 1];
    float inv = 1.f / (float)cur[d];
    ushort4 v = *(const ushort4*)&xb[(size_t)s * HDIM + 4 * q];
    atomicAdd(&agg[(size_t)d * HDIM + 4 * q + 0], bf2f(v.x) * inv);
    atomicAdd(&agg[(size_t)d * HDIM + 4 * q + 1], bf2f(v.y) * inv);
    atomicAdd(&agg[(size_t)d * HDIM + 4 * q + 2], bf2f(v.z) * inv);
    atomicAdd(&agg[(size_t)d * HDIM + 4 * q + 3], bf2f(v.w) * inv);
  }
}

__global__ __launch_bounds__(256) void k_fix2(const int* __restrict__ cntM,
                                              const int* __restrict__ ovfM,
                                              const unsigned short* __restrict__ xbM,
                                              const int* __restrict__ curM,
                                              float* __restrict__ aggM,
                                              const int* __restrict__ cntU,
                                              const int* __restrict__ ovfU,
                                              const unsigned short* __restrict__ xbU,
                                              const int* __restrict__ curU,
                                              float* __restrict__ aggU) {
  if (blockIdx.x < 16) fix_body(cntM, ovfM, xbM, curM, aggM, blockIdx.x, 16);
  else                 fix_body(cntU, ovfU, xbU, curU, aggU, blockIdx.x - 16, 16);
}

// ---------------- MFMA transform (r13 proven): out = [agg|X] @ [Wl;Wr] + b ----------------
template <int OUTBF>
__global__ __launch_bounds__(256) void k_xmfma(const float* A,
                                               const unsigned short* X,
                                               const float* __restrict__ Wl,
                                               const float* __restrict__ Wr,
                                               const float* __restrict__ bias,
                                               void* outv,
                                               int n_dst, int do_relu) {
  __shared__ unsigned short sWt[64][136];  // W^T bf16, padded
  __shared__ float sOut[4][16][68];        // per-wave C staging

  int t = threadIdx.x;
  for (int id = t; id < 64 * 128; id += 256) {
    int col = id & 63;
    int k = id >> 6;
    float wv = (k < 64) ? Wl[k * 64 + col] : Wr[(k - 64) * 64 + col];
    sWt[col][k] = f2bf(wv);
  }
  __syncthreads();

  int w = t >> 6;
  int l = t & 63;
  int lm = l & 15;
  int lg = l >> 4;
  int wid = blockIdx.x * 4 + w;
  int nw = gridDim.x * 4;
  int ntiles = (n_dst + 15) >> 4;

  for (int tile = wid; tile < ntiles; tile += nw) {
    int nbase = tile << 4;
    int row = nbase + lm;
    int rowc = row < n_dst ? row : (n_dst - 1);

    bf16x8 afr[4];
    const float* ar = A + (size_t)rowc * HDIM;
#pragma unroll
    for (int s = 0; s < 2; ++s) {
      float4 f0 = *(const float4*)(ar + 32 * s + 8 * lg);
      float4 f1 = *(const float4*)(ar + 32 * s + 8 * lg + 4);
      bf16x8 v;
      v[0] = (short)f2bf(f0.x); v[1] = (short)f2bf(f0.y);
      v[2] = (short)f2bf(f0.z); v[3] = (short)f2bf(f0.w);
      v[4] = (short)f2bf(f1.x); v[5] = (short)f2bf(f1.y);
      v[6] = (short)f2bf(f1.z); v[7] = (short)f2bf(f1.w);
      afr[s] = v;
    }
    const unsigned short* xr = X + (size_t)rowc * HDIM;
#pragma unroll
    for (int s = 0; s < 2; ++s) {
      afr[2 + s] = *(const bf16x8*)(xr + 32 * s + 8 * lg);
    }

    f32x4 zz = {0.f, 0.f, 0.f, 0.f};
    f32x4 acc[4];
#pragma unroll
    for (int n = 0; n < 4; ++n) acc[n] = zz;
#pragma unroll
    for (int s = 0; s < 4; ++s) {
#pragma unroll
      for (int n = 0; n < 4; ++n) {
        bf16x8 bfr = *(const bf16x8*)(&sWt[16 * n + lm][32 * s + 8 * lg]);
        acc[n] = __builtin_amdgcn_mfma_f32_16x16x32_bf16(afr[s], bfr, acc[n], 0, 0, 0);
      }
    }

#pragma unroll
    for (int n = 0; n < 4; ++n) {
      float bj = bias[16 * n + lm];
#pragma unroll
      for (int r = 0; r < 4; ++r) {
        float v = acc[n][r] + bj;
        if (do_relu) v = fmaxf(v, 0.f);
        sOut[w][lg * 4 + r][16 * n + lm] = v;
      }
    }

    int node = nbase + (l >> 2);
    if (node < n_dst) {
      int c0 = (l & 3) * 16;
      float4 o0 = *(const float4*)&sOut[w][l >> 2][c0];
      float4 o1 = *(const float4*)&sOut[w][l >> 2][c0 + 4];
      float4 o2 = *(const float4*)&sOut[w][l >> 2][c0 + 8];
      float4 o3 = *(const float4*)&sOut[w][l >> 2][c0 + 12];
      if (OUTBF) {
        unsigned short* ob = (unsigned short*)outv;
        uint4 p0, p1;
        p0.x = (unsigned int)f2bf(o0.x) | ((unsigned int)f2bf(o0.y) << 16);
        p0.y = (unsigned int)f2bf(o0.z) | ((unsigned int)f2bf(o0.w) << 16);
        p0.z = (unsigned int)f2bf(o1.x) | ((unsigned int)f2bf(o1.y) << 16);
        p0.w = (unsigned int)f2bf(o1.z) | ((unsigned int)f2bf(o1.w) << 16);
        p1.x = (unsigned int)f2bf(o2.x) | ((unsigned int)f2bf(o2.y) << 16);
        p1.y = (unsigned int)f2bf(o2.z) | ((unsigned int)f2bf(o2.w) << 16);
        p1.z = (unsigned int)f2bf(o3.x) | ((unsigned int)f2bf(o3.y) << 16);
        p1.w = (unsigned int)f2bf(o3.z) | ((unsigned int)f2bf(o3.w) << 16);
        *(uint4*)&ob[(size_t)node * HDIM + c0] = p0;
        *(uint4*)&ob[(size_t)node * HDIM + c0 + 8] = p1;
      } else {
        float* of = (float*)outv;
        *(float4*)&of[(size_t)node * HDIM + c0] = o0;
        *(float4*)&of[(size_t)node * HDIM + c0 + 4] = o1;
        *(float4*)&of[(size_t)node * HDIM + c0 + 8] = o2;
        *(float4*)&of[(size_t)node * HDIM + c0 + 12] = o3;
      }
    }
  }
}

// ---------------- launch ----------------

static inline int imin(int a, int b) { return a < b ? a : b; }

extern "C" void kernel_launch(void* const* d_in, const int* in_sizes, int n_in,
                              void* d_out, int out_size, void* d_ws, size_t ws_size,
                              hipStream_t stream) {
  const int NU = in_sizes[0];
  const int NM = in_sizes[1];
  const int E  = in_sizes[2];

  const int* src_um = (const int*)d_in[2];
  const int* dst_um = (const int*)d_in[3];
  const float* user_table  = (const float*)d_in[6];
  const float* movie_table = (const float*)d_in[7];
  const float* Wl1_um = (const float*)d_in[8];
  const float* Wr1_um = (const float*)d_in[9];
  const float* Wl1_mu = (const float*)d_in[10];
  const float* Wr1_mu = (const float*)d_in[11];
  const float* Wl2_um = (const float*)d_in[12];
  const float* Wr2_um = (const float*)d_in[13];
  const float* Wl2_mu = (const float*)d_in[14];
  const float* Wr2_mu = (const float*)d_in[15];
  const float* b1_um = (const float*)d_in[16];
  const float* b1_mu = (const float*)d_in[17];
  const float* b2_um = (const float*)d_in[18];
  const float* b2_mu = (const float*)d_in[19];

  float* out_u2 = (float*)d_out;                       // [NU,64]
  float* out_m2 = (float*)d_out + (size_t)NU * HDIM;   // [NM,64]
  float* aggu = out_u2;   // agg scratch in d_out; layer2 xform in-place per-row
  float* aggm = out_m2;
  // binned edge scratch also lives in d_out (dead before aggs run)
  int2* binnedM = (int2*)d_out;          // 16 MB
  int2* binnedU = (int2*)d_out + E;      // +16 MB (32 MB < 61 MB d_out)

  // workspace carve (256B aligned); total ~65 MB
  char* ws = (char*)d_ws;
  size_t off = 0;
  auto carve = [&](size_t bytes) -> char* {
    char* p = ws + off;
    off = (off + bytes + 255) & ~(size_t)255;
    return p;
  };
  int* meta = (int*)carve((size_t)(NM + NU + 2) * 4);
  int* curm = meta;
  int* curu = meta + NM;
  int* ovfm_cnt = meta + NM + NU;
  int* ovfu_cnt = meta + NM + NU + 1;
  int nmeta = NM + NU + 2;
  int* ovfm = (int*)carve((size_t)OVF_MAX * 2 * 4);
  int* ovfu = (int*)carve((size_t)OVF_MAX * 2 * 4);
  int* bktm = (int*)carve((size_t)NM * CAP_M * 4);                        // user ids (int)
  unsigned short* bktu = (unsigned short*)carve((size_t)NU * CAP_U * 2);  // movie ids (ushort)
  unsigned short* mb = (unsigned short*)carve((size_t)NM * HDIM * 2);     // bf16 movie tbl -> m1
  unsigned short* ub = (unsigned short*)carve((size_t)NU * HDIM * 2);     // bf16 user tbl -> u1
  int* ghM  = (int*)carve((size_t)NBIN * NBIN * 4);   // 1MB
  int* ghsM = (int*)carve((size_t)NBIN * NBIN * 4);   // 1MB
  int* ghU  = (int*)carve((size_t)NBIN * NBIN * 4);   // 1MB
  int* ghsU = (int*)carve((size_t)NBIN * NBIN * 4);   // 1MB
  int* part = (int*)carve(256 * 4);
  (void)ws_size;

  const int TB = 256;
  int nscan = NBIN * NBIN;             // 262144
  int nbscan = (nscan + 1023) / 1024;  // 256

  // 0) init: zero counters + bf16 table copies
  int n8u = NU * HDIM / 8, n8m = NM * HDIM / 8;
  k_init<<<3072, TB, 0, stream>>>(meta, nmeta, user_table, ub, n8u,
                                  movie_table, mb, n8m);

  // 1) fused binned build: one hist pass + two scans + one scatter pass
  k_hist2<<<NBIN, TB, 0, stream>>>(src_um, dst_um, E, NM, NU, ghM, ghU);
  k_block_sum<<<nbscan, TB, 0, stream>>>(ghM, part, nscan);
  k_scan_part<<<1, TB, 0, stream>>>(part, nbscan);
  k_scan_final<<<nbscan, TB, 0, stream>>>(ghM, part, ghsM, nscan);
  k_block_sum<<<nbscan, TB, 0, stream>>>(ghU, part, nscan);
  k_scan_part<<<1, TB, 0, stream>>>(part, nbscan);
  k_scan_final<<<nbscan, TB, 0, stream>>>(ghU, part, ghsU, nscan);
  k_scatter2<<<NBIN, TB, 0, stream>>>(src_um, dst_um, E, NM, NU,
                                      ghsM, ghsU, binnedM, binnedU);
  k_fillbin<int><<<NBIN, TB, 0, stream>>>(binnedM, ghsM, E, NM, CAP_M,
                                          bktm, curm, ovfm_cnt, ovfm);
  k_fillbin<unsigned short><<<NBIN, TB, 0, stream>>>(binnedU, ghsU, E, NU, CAP_U,
                                                     bktu, curu, ovfu_cnt, ovfu);

  int gAm = imin((NM + 31) / 32, 8192);
  int gAu = imin((NU + 31) / 32, 8192);
  int gXm = (NM + 63) / 64;   // 64 nodes/block (4 waves x 16)
  int gXu = (NU + 63) / 64;

  // 2) layer 1 (relu): serial aggs (r9 lesson), fix, MFMA xforms (in-place bf16)
  k_agg8<int><<<gAm, TB, 0, stream>>>(ub, curm, bktm, CAP_M, aggm, NM);
  k_agg8<unsigned short><<<gAu, TB, 0, stream>>>(mb, curu, bktu, CAP_U, aggu, NU);
  k_fix2<<<32, TB, 0, stream>>>(ovfm_cnt, ovfm, ub, curm, aggm,
                                ovfu_cnt, ovfu, mb, curu, aggu);
  k_xmfma<1><<<gXm, TB, 0, stream>>>(aggm, mb, Wl1_um, Wr1_um, b1_um,
                                     mb, NM, 1);   // mb becomes m1 (bf16)
  k_xmfma<1><<<gXu, TB, 0, stream>>>(aggu, ub, Wl1_mu, Wr1_mu, b1_mu,
                                     ub, NU, 1);   // ub becomes u1 (bf16)

  // 3) layer 2 (no relu): aggs into d_out, MFMA xforms in-place -> fp32 out
  k_agg8<int><<<gAm, TB, 0, stream>>>(ub, curm, bktm, CAP_M, aggm, NM);
  k_agg8<unsigned short><<<gAu, TB, 0, stream>>>(mb, curu, bktu, CAP_U, aggu, NU);
  k_fix2<<<32, TB, 0, stream>>>(ovfm_cnt, ovfm, ub, curm, aggm,
                                ovfu_cnt, ovfu, mb, curu, aggu);
  k_xmfma<0><<<gXm, TB, 0, stream>>>(aggm, mb, Wl2_um, Wr2_um, b2_um,
                                     out_m2, NM, 0);
  k_xmfma<0><<<gXu, TB, 0, stream>>>(aggu, ub, Wl2_mu, Wr2_mu, b2_mu,
                                     out_u2, NU, 0);
}